// Round 1
// baseline (80.915 us; speedup 1.0000x reference)
//
#include <hip/hip_runtime.h>
#include <math.h>

// Problem constants: M is (64, 512, 28, 28) fp32.
#define BB 64
#define CC 512
#define HH 28
#define WW 28
#define HWP 784                     // 28*28
#define NMAPS (BB*CC)               // 32768
#define NPIX  (BB*HWP)              // 50176
#define NSLOTS 512
#define NEG_FILL -999999.0f
#define NTOT 25690112.0             // 64*512*28*28

static __device__ __forceinline__ void merge_argmax(float& bv, int& bi, float ov, int oi) {
    // prefer larger value; tie -> smaller flat index (matches jnp.argmax first-index)
    if (ov > bv || (ov == bv && oi < bi)) { bv = ov; bi = oi; }
}

// ---------------- dis_loss: one wave per (b,c) map ----------------
// per map: argmax over 784 pixels + moments S0, Sy, Sx, Syy, Sxx in one pass.
// sum(M*d^2) = (iy^2+ix^2)*S0 - 2*iy*Sy - 2*ix*Sx + Syy + Sxx
__global__ __launch_bounds__(256) void dis_kernel(const float* __restrict__ M,
                                                  double* __restrict__ dis_slots) {
    const int lane = threadIdx.x & 63;
    const int wave = threadIdx.x >> 6;
    const int map  = (blockIdx.x << 2) | wave;            // 0..32767
    const float4* base = (const float4*)(M + (size_t)map * HWP);

    float bestv = -INFINITY; int besti = 0;
    float s0 = 0.f, sy = 0.f, sx = 0.f, syy = 0.f, sxx = 0.f;

    #pragma unroll
    for (int k = 0; k < 4; ++k) {
        int f = lane + (k << 6);                          // float4 index, 196 per map
        if (f < 196) {
            float4 v = base[f];
            int p0 = f << 2;
            float vv[4] = {v.x, v.y, v.z, v.w};
            #pragma unroll
            for (int j = 0; j < 4; ++j) {
                float val = vv[j];
                int pp = p0 + j;
                int y = pp / 28;
                int x = pp - y * 28;
                float fy = (float)y, fx = (float)x;
                s0  += val;
                sy  += val * fy;
                sx  += val * fx;
                syy += val * fy * fy;
                sxx += val * fx * fx;
                if (val > bestv) { bestv = val; besti = pp; }  // pp ascending per lane
            }
        }
    }
    #pragma unroll
    for (int off = 32; off >= 1; off >>= 1) {
        float ov = __shfl_down(bestv, off);
        int   oi = __shfl_down(besti, off);
        merge_argmax(bestv, besti, ov, oi);
        s0  += __shfl_down(s0,  off);
        sy  += __shfl_down(sy,  off);
        sx  += __shfl_down(sx,  off);
        syy += __shfl_down(syy, off);
        sxx += __shfl_down(sxx, off);
    }
    if (lane == 0) {
        int iy = besti / 28;
        int ix = besti - iy * 28;
        double contrib = (double)s0 * (double)(iy * iy + ix * ix)
                       - 2.0 * ((double)sy * (double)iy + (double)sx * (double)ix)
                       + (double)syy + (double)sxx;
        atomicAdd(&dis_slots[map & (NSLOTS - 1)], contrib);
    }
}

// ---------------- div_loss: per-pixel top-2 + sum over channels ----------------
// sum_c loo_c * M_c = clamp(v1)*(S - v1) + clamp(v2)*v1
// Block: 4 waves x 64 lanes. Lane owns 2 consecutive pixels (float2 loads, coalesced).
// Wave w covers channels [w*128, w*128+128). LDS merge across waves.
__global__ __launch_bounds__(256) void div_kernel(const float* __restrict__ M,
                                                  double* __restrict__ div_slots) {
    const int lane = threadIdx.x & 63;
    const int wave = threadIdx.x >> 6;                    // channel chunk 0..3
    const int pg   = blockIdx.x * 128 + lane * 2;         // global pixel index (even)
    const int b    = pg / HWP;
    const int p    = pg - b * HWP;                        // even; pair never straddles b
    const float* base = M + ((size_t)b * CC + (size_t)wave * 128) * HWP + p;

    float v1a = -INFINITY, v2a = -INFINITY, sa = 0.f;
    float v1b = -INFINITY, v2b = -INFINITY, sb = 0.f;
    #pragma unroll 4
    for (int cc = 0; cc < 128; ++cc) {
        float2 v = *(const float2*)(base + (size_t)cc * HWP);
        float xa = v.x, xb = v.y;
        sa += xa;
        if (xa > v1a) { v2a = v1a; v1a = xa; } else if (xa > v2a) { v2a = xa; }
        sb += xb;
        if (xb > v1b) { v2b = v1b; v1b = xb; } else if (xb > v2b) { v2b = xb; }
    }

    __shared__ float lds[4][64][2][3];
    lds[wave][lane][0][0] = v1a; lds[wave][lane][0][1] = v2a; lds[wave][lane][0][2] = sa;
    lds[wave][lane][1][0] = v1b; lds[wave][lane][1][1] = v2b; lds[wave][lane][1][2] = sb;
    __syncthreads();

    double contrib = 0.0;
    if (threadIdx.x < 128) {
        int l = threadIdx.x >> 1;
        int q = threadIdx.x & 1;
        float v1 = -INFINITY, v2 = -INFINITY, S = 0.f;
        #pragma unroll
        for (int w = 0; w < 4; ++w) {
            float a1 = lds[w][l][q][0], a2 = lds[w][l][q][1], as = lds[w][l][q][2];
            if (a1 > v1) { v2 = fmaxf(v1, a2); v1 = a1; }
            else         { v2 = fmaxf(v2, a1); }
            S += as;
        }
        float v1c = fmaxf(v1, NEG_FILL);
        float v2c = fmaxf(v2, NEG_FILL);
        contrib = (double)v1c * ((double)S - (double)v1) + (double)v2c * (double)v1;
    }
    #pragma unroll
    for (int off = 32; off >= 1; off >>= 1)
        contrib += __shfl_down(contrib, off);

    __shared__ double part[4];
    if (lane == 0) part[wave] = contrib;
    __syncthreads();
    if (threadIdx.x == 0)
        atomicAdd(&div_slots[blockIdx.x & (NSLOTS - 1)], part[0] + part[1] + part[2] + part[3]);
}

// ---------------- finalize: sum slots, divide by N ----------------
__global__ __launch_bounds__(512) void finalize_kernel(const double* __restrict__ slots,
                                                       float* __restrict__ out) {
    const int t = threadIdx.x;
    const int lane = t & 63, wave = t >> 6;
    double dis = slots[t];
    double div = slots[NSLOTS + t];
    #pragma unroll
    for (int off = 32; off >= 1; off >>= 1) {
        dis += __shfl_down(dis, off);
        div += __shfl_down(div, off);
    }
    __shared__ double pd[8], pv[8];
    if (lane == 0) { pd[wave] = dis; pv[wave] = div; }
    __syncthreads();
    if (t == 0) {
        double D = 0.0, V = 0.0;
        #pragma unroll
        for (int i = 0; i < 8; ++i) { D += pd[i]; V += pv[i]; }
        out[0] = (float)(D / NTOT);
        out[1] = (float)(V / NTOT);
    }
}

extern "C" void kernel_launch(void* const* d_in, const int* in_sizes, int n_in,
                              void* d_out, int out_size, void* d_ws, size_t ws_size,
                              hipStream_t stream) {
    const float* M = (const float*)d_in[0];
    double* slots = (double*)d_ws;                  // [2*NSLOTS] doubles = 8 KiB
    hipMemsetAsync(d_ws, 0, 2 * NSLOTS * sizeof(double), stream);
    dis_kernel<<<NMAPS / 4, 256, 0, stream>>>(M, slots);
    div_kernel<<<NPIX / 128, 256, 0, stream>>>(M, slots + NSLOTS);
    finalize_kernel<<<1, 512, 0, stream>>>(slots, (float*)d_out);
}

// Round 2
// 57.630 us; speedup vs baseline: 1.4040x; 1.4040x over previous
//
#include <hip/hip_runtime.h>
#include <math.h>

// M is (64, 512, 28, 28) fp32.
#define BB 64
#define CC 512
#define HWP 784                 // 28*28
#define NPIX4 12544             // (64*784)/4 float4 pixel-groups
#define NCHUNK 16               // channel chunks (32 ch each)
#define CH_PER_WAVE 8           // 32 ch per block / 4 waves
#define NSLOTS 512
#define NEG_FILL -999999.0f
#define NTOT 25690112.0         // 64*512*28*28
#define PLANE_STRIDE 200704     // NCHUNK * NPIX4 float4s per plane

// ---- per-element update: dis moments + argmax + per-pixel top-2 ----
static __device__ __forceinline__ void upd(float val, float fy, float fx, int px,
    float& s0, float& sy, float& sx, float& syy, float& sxx,
    float& bestv, int& besti, float& v1, float& v2, float& S) {
  s0 += val;
  sy  = fmaf(val, fy, sy);
  sx  = fmaf(val, fx, sx);
  syy = fmaf(val * fy, fy, syy);
  sxx = fmaf(val * fx, fx, sxx);
  if (val > bestv) { bestv = val; besti = px; }       // ascending px scan -> first index wins
  if (val > v1) { v2 = v1; v1 = val; } else { v2 = fmaxf(v2, val); }
  S += val;
}

static __device__ __forceinline__ void upd4(float4 d, float4 fy, float4 fx, int pxb,
    float& s0, float& sy, float& sx, float& syy, float& sxx,
    float& bestv, int& besti, float4& v1, float4& v2, float4& S) {
  upd(d.x, fy.x, fx.x, pxb+0, s0,sy,sx,syy,sxx,bestv,besti, v1.x,v2.x,S.x);
  upd(d.y, fy.y, fx.y, pxb+1, s0,sy,sx,syy,sxx,bestv,besti, v1.y,v2.y,S.y);
  upd(d.z, fy.z, fx.z, pxb+2, s0,sy,sx,syy,sxx,bestv,besti, v1.z,v2.z,S.z);
  upd(d.w, fy.w, fx.w, pxb+3, s0,sy,sx,syy,sxx,bestv,besti, v1.w,v2.w,S.w);
}

static __device__ __forceinline__ void coords(int f, float4& fy, float4& fx) {
  int pxb = f * 4;
  int p0 = pxb, p1 = pxb+1, p2 = pxb+2, p3 = pxb+3;
  int y0 = p0/28, y1 = p1/28, y2 = p2/28, y3 = p3/28;
  fy = make_float4((float)y0, (float)y1, (float)y2, (float)y3);
  fx = make_float4((float)(p0-y0*28), (float)(p1-y1*28), (float)(p2-y2*28), (float)(p3-y3*28));
}

// merge two (v1>=v2) pairs: top-2 of the union
static __device__ __forceinline__ void mergev(float& v1, float& v2, float b1, float b2) {
  float lo = fminf(v1, b1);
  v1 = fmaxf(v1, b1);
  v2 = fmaxf(lo, fmaxf(v2, b2));
}
static __device__ __forceinline__ void mergev4(float4& v1, float4& v2, float4 b1, float4 b2) {
  mergev(v1.x, v2.x, b1.x, b2.x);
  mergev(v1.y, v2.y, b1.y, b2.y);
  mergev(v1.z, v2.z, b1.z, b2.z);
  mergev(v1.w, v2.w, b1.w, b2.w);
}

// ---------------- fused single-pass kernel ----------------
// block = (chunk, b): 32 channels x full 784 px. 4 waves, 8 full maps per wave.
// dis: complete per-map reduction in-wave. div: per-pixel top-2 partial -> ws planes.
__global__ __launch_bounds__(256) void fused_kernel(const float* __restrict__ M,
    double* __restrict__ slots, float4* __restrict__ wsV1,
    float4* __restrict__ wsV2, float4* __restrict__ wsS) {
  const int lane  = threadIdx.x & 63;
  const int w     = threadIdx.x >> 6;
  const int chunk = blockIdx.x;
  const int b     = blockIdx.y;

  float4 FY0,FX0,FY1,FX1,FY2,FX2,FY3,FX3;
  coords(lane,       FY0, FX0);
  coords(lane + 64,  FY1, FX1);
  coords(lane + 128, FY2, FX2);
  coords(192 + (lane & 3), FY3, FX3);
  const int pxb0 = lane*4, pxb1 = (lane+64)*4, pxb2 = (lane+128)*4;
  const int pxb3 = (192 + (lane & 3))*4;

  const float NI = -INFINITY;
  float4 v10 = make_float4(NI,NI,NI,NI), v11 = v10, v12 = v10, v13 = v10;
  float4 v20 = v10, v21 = v10, v22 = v10, v23 = v10;
  float4 S0  = make_float4(0,0,0,0), S1 = S0, S2 = S0, S3 = S0;

  double dis_acc = 0.0;
  const int c0 = chunk * (CC / NCHUNK) + w * CH_PER_WAVE;
  const float* baseb = M + ((size_t)b * CC + c0) * HWP;

  #pragma unroll 4
  for (int ci = 0; ci < CH_PER_WAVE; ++ci) {
    const float4* bc = (const float4*)(baseb + (size_t)ci * HWP);
    float4 d0 = bc[lane];
    float4 d1 = bc[lane + 64];
    float4 d2 = bc[lane + 128];
    float s0 = 0.f, sy = 0.f, sx = 0.f, syy = 0.f, sxx = 0.f;
    float bestv = NI; int besti = 0;
    upd4(d0, FY0, FX0, pxb0, s0,sy,sx,syy,sxx,bestv,besti, v10,v20,S0);
    upd4(d1, FY1, FX1, pxb1, s0,sy,sx,syy,sxx,bestv,besti, v11,v21,S1);
    upd4(d2, FY2, FX2, pxb2, s0,sy,sx,syy,sxx,bestv,besti, v12,v22,S2);
    if (lane < 4) {
      float4 d3 = bc[192 + lane];
      upd4(d3, FY3, FX3, pxb3, s0,sy,sx,syy,sxx,bestv,besti, v13,v23,S3);
    }
    // per-channel wave reduction (moments + argmax)
    #pragma unroll
    for (int off = 32; off >= 1; off >>= 1) {
      float ov = __shfl_down(bestv, off);
      int   oi = __shfl_down(besti, off);
      if (ov > bestv || (ov == bestv && oi < besti)) { bestv = ov; besti = oi; }
      s0  += __shfl_down(s0 , off);
      sy  += __shfl_down(sy , off);
      sx  += __shfl_down(sx , off);
      syy += __shfl_down(syy, off);
      sxx += __shfl_down(sxx, off);
    }
    if (lane == 0) {
      int iy = besti / 28;
      int ix = besti - iy * 28;
      dis_acc += (double)s0 * (double)(iy*iy + ix*ix)
               - 2.0 * ((double)sy * (double)iy + (double)sx * (double)ix)
               + (double)syy + (double)sxx;
    }
  }
  if (lane == 0)
    atomicAdd(&slots[(((b * NCHUNK) + chunk) * 4 + w) & (NSLOTS - 1)], dis_acc);

  // cross-wave merge of per-pixel top-2 partials (this block's 32-channel chunk)
  __shared__ float4 lm[4][3][196];
  lm[w][0][lane] = v10; lm[w][0][lane+64] = v11; lm[w][0][lane+128] = v12;
  lm[w][1][lane] = v20; lm[w][1][lane+64] = v21; lm[w][1][lane+128] = v22;
  lm[w][2][lane] = S0;  lm[w][2][lane+64] = S1;  lm[w][2][lane+128] = S2;
  if (lane < 4) {
    lm[w][0][192+lane] = v13; lm[w][1][192+lane] = v23; lm[w][2][192+lane] = S3;
  }
  __syncthreads();

  const int t = threadIdx.x;
  if (t < 196) {
    float4 mv1 = lm[0][0][t], mv2 = lm[0][1][t], mS = lm[0][2][t];
    #pragma unroll
    for (int ww = 1; ww < 4; ++ww) {
      float4 b1 = lm[ww][0][t], b2 = lm[ww][1][t], bS = lm[ww][2][t];
      mergev4(mv1, mv2, b1, b2);
      mS.x += bS.x; mS.y += bS.y; mS.z += bS.z; mS.w += bS.w;
    }
    const int idx = chunk * NPIX4 + b * 196 + t;
    wsV1[idx] = mv1; wsV2[idx] = mv2; wsS[idx] = mS;
  }
}

// ---------------- merge chunk partials -> div contribs ----------------
__global__ __launch_bounds__(256) void div_merge_kernel(const float4* __restrict__ wsV1,
    const float4* __restrict__ wsV2, const float4* __restrict__ wsS,
    double* __restrict__ slots) {
  const int g = blockIdx.x * 256 + threadIdx.x;     // 0..12543 float4 pixel-group
  const int lane = threadIdx.x & 63, w = threadIdx.x >> 6;
  float4 v1 = wsV1[g], v2 = wsV2[g], S = wsS[g];
  #pragma unroll 5
  for (int c = 1; c < NCHUNK; ++c) {
    const int idx = c * NPIX4 + g;
    float4 b1 = wsV1[idx], b2 = wsV2[idx], bS = wsS[idx];
    mergev4(v1, v2, b1, b2);
    S.x += bS.x; S.y += bS.y; S.z += bS.z; S.w += bS.w;
  }
  // sum_c loo_c * M_c = clamp(v1)*(S - v1) + clamp(v2)*v1  (per pixel)
  double contrib =
      (double)fmaxf(v1.x, NEG_FILL) * ((double)S.x - (double)v1.x) + (double)fmaxf(v2.x, NEG_FILL) * (double)v1.x
    + (double)fmaxf(v1.y, NEG_FILL) * ((double)S.y - (double)v1.y) + (double)fmaxf(v2.y, NEG_FILL) * (double)v1.y
    + (double)fmaxf(v1.z, NEG_FILL) * ((double)S.z - (double)v1.z) + (double)fmaxf(v2.z, NEG_FILL) * (double)v1.z
    + (double)fmaxf(v1.w, NEG_FILL) * ((double)S.w - (double)v1.w) + (double)fmaxf(v2.w, NEG_FILL) * (double)v1.w;

  #pragma unroll
  for (int off = 32; off >= 1; off >>= 1)
    contrib += __shfl_down(contrib, off);
  __shared__ double part[4];
  if (lane == 0) part[w] = contrib;
  __syncthreads();
  if (threadIdx.x == 0)
    atomicAdd(&slots[NSLOTS + (blockIdx.x & (NSLOTS - 1))],
              part[0] + part[1] + part[2] + part[3]);
}

// ---------------- finalize ----------------
__global__ __launch_bounds__(512) void finalize_kernel(const double* __restrict__ slots,
                                                       float* __restrict__ out) {
  const int t = threadIdx.x;
  const int lane = t & 63, wave = t >> 6;
  double dis = slots[t];
  double dv  = slots[NSLOTS + t];
  #pragma unroll
  for (int off = 32; off >= 1; off >>= 1) {
    dis += __shfl_down(dis, off);
    dv  += __shfl_down(dv,  off);
  }
  __shared__ double pd[8], pv[8];
  if (lane == 0) { pd[wave] = dis; pv[wave] = dv; }
  __syncthreads();
  if (t == 0) {
    double D = 0.0, V = 0.0;
    #pragma unroll
    for (int i = 0; i < 8; ++i) { D += pd[i]; V += pv[i]; }
    out[0] = (float)(D / NTOT);
    out[1] = (float)(V / NTOT);
  }
}

extern "C" void kernel_launch(void* const* d_in, const int* in_sizes, int n_in,
                              void* d_out, int out_size, void* d_ws, size_t ws_size,
                              hipStream_t stream) {
  const float* M = (const float*)d_in[0];
  double* slots = (double*)d_ws;                          // 1024 doubles
  float4* planes = (float4*)((char*)d_ws + 16384);        // 3 planes of PLANE_STRIDE float4
  hipMemsetAsync(d_ws, 0, 2 * NSLOTS * sizeof(double), stream);
  fused_kernel<<<dim3(NCHUNK, BB), 256, 0, stream>>>(
      M, slots, planes, planes + PLANE_STRIDE, planes + 2 * PLANE_STRIDE);
  div_merge_kernel<<<NPIX4 / 256, 256, 0, stream>>>(
      planes, planes + PLANE_STRIDE, planes + 2 * PLANE_STRIDE, slots);
  finalize_kernel<<<1, 512, 0, stream>>>(slots, (float*)d_out);
}

// Round 3
// 43.375 us; speedup vs baseline: 1.8655x; 1.3286x over previous
//
#include <hip/hip_runtime.h>
#include <math.h>

// M is (64, 512, 28, 28) fp32.
#define BB 64
#define CC 512
#define HWP 784                 // 28*28
#define NPIX4 12544             // (64*784)/4 float4 pixel-groups
#define NCHUNK 16               // channel chunks (32 ch each)
#define NSLOTS 512
#define NEG_FILL -999999.0f
#define NTOT 25690112.0         // 64*512*28*28
#define PLANE_STRIDE 200704     // NCHUNK * NPIX4 float4s per plane

static __device__ __forceinline__ unsigned sortable(float v) {
  unsigned b = __float_as_uint(v);
  return (b & 0x80000000u) ? ~b : (b | 0x80000000u);
}

// branchless top-2 insert: 3 ops
static __device__ __forceinline__ void top2(float v, float& v1, float& v2) {
  float lo = fminf(v, v1);
  v1 = fmaxf(v1, v);
  v2 = fmaxf(v2, lo);
}

// merge two (v1>=v2) pairs: top-2 of the union
static __device__ __forceinline__ void mergev(float& v1, float& v2, float b1, float b2) {
  float lo = fminf(v1, b1);
  v1 = fmaxf(v1, b1);
  v2 = fmaxf(lo, fmaxf(v2, b2));
}
static __device__ __forceinline__ void mergev4(float4& v1, float4& v2, float4 b1, float4 b2) {
  mergev(v1.x, v2.x, b1.x, b2.x);
  mergev(v1.y, v2.y, b1.y, b2.y);
  mergev(v1.z, v2.z, b1.z, b2.z);
  mergev(v1.w, v2.w, b1.w, b2.w);
}

// ---------------- fused single-pass kernel ----------------
// block = (chunk, b): 32 channels x 784 px; 4 waves, 8 ch/wave.
// Position-chunk outer loop -> 8 loads in flight; per-channel state = per-lane
// partial moments + argmax only. Cross-lane work: 1 u64 butterfly per channel.
__global__ __launch_bounds__(256, 4) void fused_kernel(const float* __restrict__ M,
    double* __restrict__ slots, float4* __restrict__ wsV1,
    float4* __restrict__ wsV2, float4* __restrict__ wsS) {
  const int lane  = threadIdx.x & 63;
  const int w     = threadIdx.x >> 6;
  const int chunk = blockIdx.x;
  const int b     = blockIdx.y;
  const float* base = M + ((size_t)b * CC + chunk * 32 + w * 8) * HWP;

  float s0[8], sy[8], sx[8], bv[8];
  int bi[8];
  #pragma unroll
  for (int c = 0; c < 8; ++c) { s0[c]=0.f; sy[c]=0.f; sx[c]=0.f; bv[c]=-INFINITY; bi[c]=0; }
  float srr = 0.f;                       // sum of M*(y^2+x^2) over all 8 maps (lane slice)

  __shared__ float4 lm[4][3][196];

  auto process = [&](int f) {
    const int y  = f / 7;                // 4|28: all 4 px of a float4 share y
    const int x0 = (f - y * 7) * 4;
    const float fy  = (float)y;
    const float fx0 = (float)x0, fx1 = fx0 + 1.f, fx2 = fx0 + 2.f, fx3 = fx0 + 3.f;
    const float fyy = fy * fy;
    const float rr0 = fyy + fx0*fx0, rr1 = fyy + fx1*fx1;
    const float rr2 = fyy + fx2*fx2, rr3 = fyy + fx3*fx3;
    const int pxb = f * 4;

    float4 d[8];
    #pragma unroll
    for (int c = 0; c < 8; ++c)
      d[c] = *(const float4*)(base + c * HWP + pxb);

    const float NI = -INFINITY;
    float4 v1 = make_float4(NI, NI, NI, NI);
    float4 v2 = v1;
    float4 S  = make_float4(0.f, 0.f, 0.f, 0.f);

    #pragma unroll
    for (int c = 0; c < 8; ++c) {
      const float a0 = d[c].x, a1 = d[c].y, a2 = d[c].z, a3 = d[c].w;
      const float sum4 = (a0 + a1) + (a2 + a3);
      s0[c] += sum4;
      sy[c] = fmaf(sum4, fy, sy[c]);                 // shared y
      sx[c] = fmaf(a0, fx0, sx[c]); sx[c] = fmaf(a1, fx1, sx[c]);
      sx[c] = fmaf(a2, fx2, sx[c]); sx[c] = fmaf(a3, fx3, sx[c]);
      srr = fmaf(a0, rr0, srr); srr = fmaf(a1, rr1, srr);
      srr = fmaf(a2, rr2, srr); srr = fmaf(a3, rr3, srr);
      if (a0 > bv[c]) { bv[c] = a0; bi[c] = pxb;     }
      if (a1 > bv[c]) { bv[c] = a1; bi[c] = pxb + 1; }
      if (a2 > bv[c]) { bv[c] = a2; bi[c] = pxb + 2; }
      if (a3 > bv[c]) { bv[c] = a3; bi[c] = pxb + 3; }
      top2(a0, v1.x, v2.x); S.x += a0;
      top2(a1, v1.y, v2.y); S.y += a1;
      top2(a2, v1.z, v2.z); S.z += a2;
      top2(a3, v1.w, v2.w); S.w += a3;
    }
    lm[w][0][f] = v1; lm[w][1][f] = v2; lm[w][2][f] = S;
  };

  #pragma unroll
  for (int k = 0; k < 3; ++k) process(lane + 64 * k);
  if (lane < 4) process(192 + lane);

  // ---- dis epilogue: argmax butterfly per channel, lane-local contribution ----
  double dis_acc = (double)srr;
  #pragma unroll
  for (int c = 0; c < 8; ++c) {
    unsigned long long key =
        ((unsigned long long)sortable(bv[c]) << 32) | (unsigned)(~bi[c]);
    #pragma unroll
    for (int off = 1; off < 64; off <<= 1) {
      unsigned long long o = __shfl_xor(key, off);
      key = (key > o) ? key : o;                    // max val; tie -> min index
    }
    const int px = (int)(~((unsigned)key));
    const int iy = px / 28;
    const int ix = px - iy * 28;
    dis_acc += (double)s0[c] * (double)(iy * iy + ix * ix)
             - 2.0 * ((double)sy[c] * (double)iy + (double)sx[c] * (double)ix);
  }
  #pragma unroll
  for (int off = 32; off >= 1; off >>= 1)
    dis_acc += __shfl_down(dis_acc, off);
  if (lane == 0)
    atomicAdd(&slots[(((b * NCHUNK) + chunk) * 4 + w) & (NSLOTS - 1)], dis_acc);

  // ---- cross-wave merge of per-pixel top-2 partials ----
  __syncthreads();
  const int t = threadIdx.x;
  if (t < 196) {
    float4 mv1 = lm[0][0][t], mv2 = lm[0][1][t], mS = lm[0][2][t];
    #pragma unroll
    for (int ww = 1; ww < 4; ++ww) {
      mergev4(mv1, mv2, lm[ww][0][t], lm[ww][1][t]);
      float4 bS = lm[ww][2][t];
      mS.x += bS.x; mS.y += bS.y; mS.z += bS.z; mS.w += bS.w;
    }
    const int idx = chunk * NPIX4 + b * 196 + t;
    wsV1[idx] = mv1; wsV2[idx] = mv2; wsS[idx] = mS;
  }
}

// ---------------- merge chunk partials -> div contribs ----------------
// 196 blocks; wave w folds chunks 4w..4w+3 for 64 pixel-groups; LDS fold of 4 waves.
__global__ __launch_bounds__(256) void div_merge_kernel(const float4* __restrict__ wsV1,
    const float4* __restrict__ wsV2, const float4* __restrict__ wsS,
    double* __restrict__ slots) {
  const int t = threadIdx.x, lane = t & 63, w = t >> 6;
  const int g = blockIdx.x * 64 + lane;

  float4 a1[4], a2[4], aS[4];
  #pragma unroll
  for (int c = 0; c < 4; ++c) {
    const int idx = (w * 4 + c) * NPIX4 + g;
    a1[c] = wsV1[idx]; a2[c] = wsV2[idx]; aS[c] = wsS[idx];
  }
  float4 v1 = a1[0], v2 = a2[0], S = aS[0];
  #pragma unroll
  for (int c = 1; c < 4; ++c) {
    mergev4(v1, v2, a1[c], a2[c]);
    S.x += aS[c].x; S.y += aS[c].y; S.z += aS[c].z; S.w += aS[c].w;
  }
  __shared__ float4 sm[4][3][64];
  sm[w][0][lane] = v1; sm[w][1][lane] = v2; sm[w][2][lane] = S;
  __syncthreads();

  if (t < 64) {
    v1 = sm[0][0][t]; v2 = sm[0][1][t]; S = sm[0][2][t];
    #pragma unroll
    for (int ww = 1; ww < 4; ++ww) {
      mergev4(v1, v2, sm[ww][0][t], sm[ww][1][t]);
      float4 bS = sm[ww][2][t];
      S.x += bS.x; S.y += bS.y; S.z += bS.z; S.w += bS.w;
    }
    // sum_c loo_c*M_c = clamp(v1)*(S - v1) + clamp(v2)*v1   (per pixel)
    double contrib =
        (double)fmaxf(v1.x, NEG_FILL) * ((double)S.x - (double)v1.x) + (double)fmaxf(v2.x, NEG_FILL) * (double)v1.x
      + (double)fmaxf(v1.y, NEG_FILL) * ((double)S.y - (double)v1.y) + (double)fmaxf(v2.y, NEG_FILL) * (double)v1.y
      + (double)fmaxf(v1.z, NEG_FILL) * ((double)S.z - (double)v1.z) + (double)fmaxf(v2.z, NEG_FILL) * (double)v1.z
      + (double)fmaxf(v1.w, NEG_FILL) * ((double)S.w - (double)v1.w) + (double)fmaxf(v2.w, NEG_FILL) * (double)v1.w;
    #pragma unroll
    for (int off = 32; off >= 1; off >>= 1)
      contrib += __shfl_down(contrib, off);
    if (t == 0)
      atomicAdd(&slots[NSLOTS + blockIdx.x], contrib);
  }
}

// ---------------- finalize ----------------
__global__ __launch_bounds__(512) void finalize_kernel(const double* __restrict__ slots,
                                                       float* __restrict__ out) {
  const int t = threadIdx.x;
  const int lane = t & 63, wave = t >> 6;
  double dis = slots[t];
  double dv  = slots[NSLOTS + t];
  #pragma unroll
  for (int off = 32; off >= 1; off >>= 1) {
    dis += __shfl_down(dis, off);
    dv  += __shfl_down(dv,  off);
  }
  __shared__ double pd[8], pv[8];
  if (lane == 0) { pd[wave] = dis; pv[wave] = dv; }
  __syncthreads();
  if (t == 0) {
    double D = 0.0, V = 0.0;
    #pragma unroll
    for (int i = 0; i < 8; ++i) { D += pd[i]; V += pv[i]; }
    out[0] = (float)(D / NTOT);
    out[1] = (float)(V / NTOT);
  }
}

extern "C" void kernel_launch(void* const* d_in, const int* in_sizes, int n_in,
                              void* d_out, int out_size, void* d_ws, size_t ws_size,
                              hipStream_t stream) {
  const float* M = (const float*)d_in[0];
  double* slots = (double*)d_ws;                          // 1024 doubles
  float4* planes = (float4*)((char*)d_ws + 16384);        // 3 planes of PLANE_STRIDE float4
  hipMemsetAsync(d_ws, 0, 2 * NSLOTS * sizeof(double), stream);
  fused_kernel<<<dim3(NCHUNK, BB), 256, 0, stream>>>(
      M, slots, planes, planes + PLANE_STRIDE, planes + 2 * PLANE_STRIDE);
  div_merge_kernel<<<196, 256, 0, stream>>>(
      planes, planes + PLANE_STRIDE, planes + 2 * PLANE_STRIDE, slots);
  finalize_kernel<<<1, 512, 0, stream>>>(slots, (float*)d_out);
}